// Round 8
// baseline (324.903 us; speedup 1.0000x reference)
//
#include <hip/hip_runtime.h>
#include <hip/hip_bf16.h>
#include <stdint.h>

// Problem constants (fixed by the reference file)
#define NB 8     // batch
#define NS 2048  // sequence
#define ND 1536  // model dim (K)
#define NT 2048  // padded tracks (N)
#define NH 8     // heads
#define NK2 (ND / 64)  // 24 K-iterations at BK=64

// NUM_TRACKS = [128,256,512,1024,2048,64,32,1024] -> ceil(nt/128) (in 128-tiles)
__constant__ int c_tiles[NH] = {1, 2, 4, 8, 16, 1, 1, 8};

typedef short bf16x8 __attribute__((ext_vector_type(8)));  // 8 bf16 (4 VGPRs)
typedef unsigned short u16x8 __attribute__((ext_vector_type(8)));
typedef float f32x4 __attribute__((ext_vector_type(4)));

__device__ __forceinline__ unsigned short f2bf(float f) {
    union { float f; unsigned u; } a; a.f = f;
    unsigned r = a.u + 0x7fffu + ((a.u >> 16) & 1u);  // RNE
    return (unsigned short)(r >> 16);
}

// ---------------- Fused prepass: x fp32->bf16  +  W transpose+convert -------
#define XBLK 24576
__global__ void cvt_kernel(const float* __restrict__ x,
                           const float* __restrict__ W,
                           const int* __restrict__ hidx,
                           unsigned short* __restrict__ xb,
                           unsigned short* __restrict__ Wt) {
    const int bid = blockIdx.x;
    const int tid = threadIdx.x;
    if (bid < XBLK) {
        const size_t i = (size_t)bid * 256 + tid;  // float4 index
        float4 v = ((const float4*)x)[i];
        ushort4 o;
        o.x = f2bf(v.x); o.y = f2bf(v.y); o.z = f2bf(v.z); o.w = f2bf(v.w);
        ((ushort4*)xb)[i] = o;
        return;
    }
    // W transpose: wid -> (t-tile 32, d-tile 24, h 8)
    const int wid = bid - XBLK;
    const int h = wid / (32 * 24);
    const int rem = wid % (32 * 24);
    const int t0 = (rem % 32) * 64;
    const int d0 = (rem / 32) * 64;
    bool used = false;
    for (int i = 0; i < NB; ++i) used |= (hidx[i] == h);
    if (!used || t0 >= c_tiles[h] * 128) return;

    __shared__ float tile[64][69];  // [d][t], padded
#pragma unroll
    for (int i = 0; i < 4; ++i) {
        const int idx = tid + i * 256;  // 1024 float4 chunks
        const int d = idx >> 4, c = (idx & 15) * 4;
        float4 v = *(const float4*)&W[((size_t)h * ND + d0 + d) * NT + t0 + c];
        tile[d][c] = v.x; tile[d][c + 1] = v.y;
        tile[d][c + 2] = v.z; tile[d][c + 3] = v.w;
    }
    __syncthreads();
    const int t = tid >> 2, dc = (tid & 3) * 16;  // 16 bf16 = 32 B per thread
    u16x8 o0, o1;
#pragma unroll
    for (int j = 0; j < 8; ++j) o0[j] = f2bf(tile[dc + j][t]);
#pragma unroll
    for (int j = 0; j < 8; ++j) o1[j] = f2bf(tile[dc + 8 + j][t]);
    unsigned short* p = Wt + ((size_t)h * NT + t0 + t) * ND + d0 + dc;
    *(u16x8*)p = o0;
    *(u16x8*)(p + 8) = o1;
}

// ---------------- GEMM: out[b] = x[b] @ W[h(b)] + bias[h(b)] ----------------
// 256x128 tile, 8 waves (512 thr), per-wave 64x64 (proven geometry), BK=64.
// TRIPLE-buffered LDS (3 x 48 KiB = 144 KiB): tile t+2 is issued BEFORE
// computing tile t, so every tile's loads get TWO full iterations of slack
// (~4000 cyc) instead of one COMPUTE phase (~1500) -- the residual latency
// exposure that capped rounds 4-7 (iter ~7000 cyc vs ~2100 cyc LDS/MFMA
// floor). Steady state: PREFETCH(t+2); WAITV(12) [oldest-first => tile t
// landed]; BAR (publish); COMPUTE(t); BAR (free buf for t+3).
// T1: bijective XCD chunk-swizzle. T5: setprio around MFMA clusters.
#define GLDS(g, l)                                                      \
    __builtin_amdgcn_global_load_lds(                                   \
        (const __attribute__((address_space(1))) void*)(g),             \
        (__attribute__((address_space(3))) void*)(l), 16, 0, 0)

#define BAR()                                                           \
    do {                                                                \
        asm volatile("" ::: "memory");                                  \
        __builtin_amdgcn_s_barrier();                                   \
        asm volatile("" ::: "memory");                                  \
    } while (0)
#define WAITV(N) asm volatile("s_waitcnt vmcnt(" #N ")" ::: "memory")

__global__ __launch_bounds__(512) void gemm_kernel(
    const unsigned short* __restrict__ xb,   // bf16 [NB][NS][ND]
    const unsigned short* __restrict__ wt,   // bf16 [NH][NT][ND]
    const float* __restrict__ bias,          // fp32 [NH][NT]
    const int* __restrict__ hidx,            // [NB]
    float* __restrict__ out)                 // fp32 [NB][NS][NT]
{
    const int tid = threadIdx.x;
    const int id = blockIdx.x;

    int hh[NB], tl[NB];
    int P = 0;
#pragma unroll
    for (int b = 0; b < NB; ++b) {
        hh[b] = hidx[b];
        tl[b] = c_tiles[hh[b]];
        P += tl[b];
    }
    const int C = 8 * P;  // 8 m-tiles of 256 rows

    int batch, m0, n0;
    if (id >= C) {
        // ---- zero tile: 256x128 of exact zeros ----
        const int Pz = 128 - P;
        const int z = id - C;
        int p = z % Pz;
        const int m = z / Pz;
        int b = 0;
        while (p >= 16 - tl[b]) { p -= 16 - tl[b]; ++b; }
        batch = b; n0 = (tl[b] + p) * 128; m0 = m * 256;
        float* outb = out + (size_t)batch * NS * NT;
        const int row = tid >> 1;
        const int c0 = (tid & 1) * 64;
        float4 zv = make_float4(0.f, 0.f, 0.f, 0.f);
        float4* ptr = (float4*)(outb + (size_t)(m0 + row) * NT + (n0 + c0));
#pragma unroll
        for (int j = 0; j < 16; ++j) ptr[j] = zv;
        return;
    }
    {
        // T1: bijective chunk-swizzle over [0, C): XCD k owns a contiguous
        // logical range -> consecutive m-panels stay in one XCD's L2.
        const int q8 = C >> 3, r8 = C & 7;
        const int xcd = id & 7, i8 = id >> 3;
        const int sid = (xcd < r8 ? xcd * (q8 + 1) : r8 * (q8 + 1) + (xcd - r8) * q8) + i8;
        int p = sid % P;
        const int m = sid / P;
        int b = 0;
        while (p >= tl[b]) { p -= tl[b]; ++b; }
        batch = b; n0 = p * 128; m0 = m * 256;
    }
    const int h = hh[batch];
    float* outb = out + (size_t)batch * NS * NT;

    // Triple-buffered LDS: 3 x (32 KiB A + 16 KiB B) = 144 KiB
    __shared__ unsigned short As[3][256 * 64];  // [m][k], k-chunks XOR-swizzled
    __shared__ unsigned short Bs[3][128 * 64];  // [n][k] (B^T), swizzled

    const int lane = tid & 63;
    const int wave = tid >> 6;         // 0..7
    const int wm = (wave >> 1) * 64;   // 4 m-waves over 256 rows
    const int wn = (wave & 1) * 64;    // 2 n-waves over 128 cols
    const int fr = lane & 15;
    const int q = lane >> 4;           // k-group 0..3

    // Staging: A = 2048 16B chunks (4/thread), B = 1024 (2/thread) -> 6/thread.
    // LDS slot c=(row,sc) holds global k-chunk gc = sc ^ (row&7)  [bank swizzle]
    const unsigned short* ga[4];
    int ca[4];
#pragma unroll
    for (int j = 0; j < 4; ++j) {
        const int c = tid + 512 * j;
        const int r = c >> 3, gc = (c & 7) ^ (r & 7);
        ga[j] = xb + ((size_t)batch * NS + m0 + r) * ND + gc * 8;
        ca[j] = c * 8;
    }
    const unsigned short* gb[2];
    int cb[2];
#pragma unroll
    for (int j = 0; j < 2; ++j) {
        const int c = tid + 512 * j;
        const int r = c >> 3, gc = (c & 7) ^ (r & 7);
        gb[j] = wt + ((size_t)h * NT + n0 + r) * ND + gc * 8;
        cb[j] = c * 8;
    }

    // Reader-side swizzled k-offsets (shorts) for kk=0 / kk=1 sub-tiles.
    const int sw0 = ((q) ^ (fr & 7)) * 8;
    const int sw1 = ((q + 4) ^ (fr & 7)) * 8;

    f32x4 acc[4][4] = {};

#define PREFETCH(B)                                                   \
    do {                                                              \
        _Pragma("unroll")                                             \
        for (int j = 0; j < 4; ++j) GLDS(ga[j], &As[B][ca[j]]);       \
        _Pragma("unroll")                                             \
        for (int j = 0; j < 2; ++j) GLDS(gb[j], &Bs[B][cb[j]]);       \
        _Pragma("unroll")                                             \
        for (int j = 0; j < 4; ++j) ga[j] += 64;                      \
        _Pragma("unroll")                                             \
        for (int j = 0; j < 2; ++j) gb[j] += 64;                      \
    } while (0)

#define COMPUTE(B)                                                            \
    do {                                                                      \
        _Pragma("unroll")                                                     \
        for (int kk = 0; kk < 2; ++kk) {                                      \
            const int sw = kk ? sw1 : sw0;                                    \
            bf16x8 af[4], bfr[4];                                             \
            _Pragma("unroll")                                                 \
            for (int mi = 0; mi < 4; ++mi)                                    \
                af[mi] = *(const bf16x8*)(&As[B][(wm + mi * 16 + fr) * 64 + sw]); \
            _Pragma("unroll")                                                 \
            for (int ni = 0; ni < 4; ++ni)                                    \
                bfr[ni] = *(const bf16x8*)(&Bs[B][(wn + ni * 16 + fr) * 64 + sw]); \
            __builtin_amdgcn_s_setprio(1);                                    \
            _Pragma("unroll")                                                 \
            for (int mi = 0; mi < 4; ++mi)                                    \
                _Pragma("unroll")                                             \
                for (int ni = 0; ni < 4; ++ni)                                \
                    acc[mi][ni] = __builtin_amdgcn_mfma_f32_16x16x32_bf16(    \
                        af[mi], bfr[ni], acc[mi][ni], 0, 0, 0);               \
            __builtin_amdgcn_s_setprio(0);                                    \
        }                                                                     \
    } while (0)

    // Prologue: tiles 0,1 in flight; WAITV(6) -> tile 0 landed (tile 1's 6
    // loads stay outstanding); publish buf0.
    PREFETCH(0);
    PREFETCH(1);
    WAITV(6);
    BAR();

    // Steady state, t = 0..20 (7 unrolled triples, static buffer indices).
    // Per tile t: issue tile t+2 into buf[(t+2)%3] (freed by the barrier
    // after COMPUTE(t-1)); WAITV(12) -> tiles t+1,t+2 outstanding => tile t
    // complete (vmcnt drains oldest-first); BAR publishes tile t; COMPUTE(t);
    // BAR frees buf[t%3] for tile t+3.
    for (int it = 0; it < 7; ++it) {
        PREFETCH(2); WAITV(12); BAR(); COMPUTE(0); BAR();
        PREFETCH(0); WAITV(12); BAR(); COMPUTE(1); BAR();
        PREFETCH(1); WAITV(12); BAR(); COMPUTE(2); BAR();
    }
    // t=21: prefetch tile 23 (last) into buf2.
    PREFETCH(2); WAITV(12); BAR(); COMPUTE(0); BAR();
    // t=22: outstanding = tile 23's 6 loads.
    WAITV(6); BAR(); COMPUTE(1); BAR();
    // t=23: drain.
    WAITV(0); BAR(); COMPUTE(2);

#undef PREFETCH
#undef COMPUTE

    // Epilogue: C/D layout col=lane&15, row=(lane>>4)*4+reg
    float bv[4];
#pragma unroll
    for (int ni = 0; ni < 4; ++ni)
        bv[ni] = bias[(size_t)h * NT + n0 + wn + ni * 16 + fr];

    const int rbase = m0 + wm + q * 4;
#pragma unroll
    for (int mi = 0; mi < 4; ++mi) {
#pragma unroll
        for (int r = 0; r < 4; ++r) {
            float* op = outb + (size_t)(rbase + mi * 16 + r) * NT + n0 + wn + fr;
#pragma unroll
            for (int ni = 0; ni < 4; ++ni)
                op[ni * 16] = acc[mi][ni][r] + bv[ni];
        }
    }
}

extern "C" void kernel_launch(void* const* d_in, const int* in_sizes, int n_in,
                              void* d_out, int out_size, void* d_ws, size_t ws_size,
                              hipStream_t stream) {
    const float* x    = (const float*)d_in[0];  // [NB][NS][ND] fp32
    const int*   hidx = (const int*)d_in[1];    // [NB] int32
    const float* W    = (const float*)d_in[2];  // [NH][ND][NT] fp32
    const float* bias = (const float*)d_in[3];  // [NH][NT] fp32
    float* out = (float*)d_out;

    unsigned short* xb = (unsigned short*)d_ws;            // 48 MiB bf16 x
    unsigned short* wt = xb + (size_t)NB * NS * ND;        // 48 MiB bf16 W^T

    // Fused convert: 24576 x-blocks + 6144 W-blocks
    cvt_kernel<<<dim3(XBLK + 32 * 24 * NH), dim3(256), 0, stream>>>(
        x, W, hidx, xb, wt);
    // GEMM: 1024 blocks = 8 m-tiles x 16 n-tiles x 8 batches, balanced decode
    gemm_kernel<<<dim3(1024), dim3(512), 0, stream>>>(xb, wt, bias, hidx, out);
}